// Round 14
// baseline (967.586 us; speedup 1.0000x reference)
//
#include <hip/hip_runtime.h>

constexpr int T = 36, P = 64, H = 128, W = 256;
constexpr int HW  = H * W;        // 32768
constexpr int PHW = P * HW;       // 2097152

constexpr int TH   = 16;          // rows per band
constexpr int NB   = 8;           // bands per plane
constexpr int NBLK = P * NB;      // 512 blocks (2 per CU), 512 threads each
// sx/sh: storage row = spatial + 4 (spatial -4..19 -> 0..23; row 24 = zero pad)
//        storage col = spatial + 6 (in-image 0..255 -> 6..261; pads stay 0)
constexpr int SR = 25, SC = 268;
// srh: storage row = spatial + 2 (spatial -2..17 -> 0..19), same col mapping
constexpr int RR = 20;

constexpr long long TMO_ARRIVE = 3000000;   // ~30 ms @100MHz wall clock
constexpr long long TMO_STEP   = 1000000;   // ~10 ms

typedef float vfloat4 __attribute__((ext_vector_type(4)));

__device__ __forceinline__ float fast_sigmoid(float z) {
    float e = __expf(-z);
    return __builtin_amdgcn_rcpf(1.0f + e);
}
__device__ __forceinline__ float fast_tanh(float x) {
    float e = __expf(-2.0f * fabsf(x));
    float t = (1.0f - e) * __builtin_amdgcn_rcpf(1.0f + e);
    return copysignf(t, x);
}

__device__ __forceinline__ void lds_store4(float* d, float4 v) {
    // 8B-aligned LDS store of 16B (storage col base ≡ 2 mod 4)
    *(float2*)d       = make_float2(v.x, v.y);
    *(float2*)(d + 2) = make_float2(v.z, v.w);
}

__global__ __launch_bounds__(512, 4) void gru_all(
    const float* __restrict__ inputs, const float* __restrict__ gam,
    const float* __restrict__ w_update, const float* __restrict__ b_update,
    const float* __restrict__ w_reset,  const float* __restrict__ b_reset,
    const float* __restrict__ w_out,    const float* __restrict__ add_w,
    float* __restrict__ xs, float* __restrict__ hhalo, int* __restrict__ flags)
{
    __shared__ __align__(16) float sx[SR][SC];
    __shared__ __align__(16) float sh[SR][SC];
    __shared__ __align__(16) float srh[RR][SC];
    __shared__ int s_nowait;
    __shared__ int s_haloready;   // monotone: halo rows for step t are in LDS when >= t

    const int tid  = threadIdx.x;
    const int bid  = blockIdx.x;
    const int p    = bid >> 3;
    const int band = bid & 7;
    const int y0   = band * TH;

    const float gamma = gam[p];
    const float bu = b_update[0];
    const float br = b_reset[0];

    const int lane = tid & 63, rbb = tid >> 6;  // wave id 0..7
    const int ox = 4 * lane, oy = 2 * rbb;      // ph2 mapping: 2x4 px per thread

    int* flagsTop = flags;
    int* flagsBot = flags + NBLK;

    // ---- arrival barrier (relaxed counting) with timeout ----
    if (tid == 0) {
        s_nowait = 0;
        s_haloready = 0;
        __hip_atomic_fetch_add(&flags[2 * NBLK], 1, __ATOMIC_RELAXED, __HIP_MEMORY_SCOPE_AGENT);
        const long long t0 = (long long)__builtin_amdgcn_s_memrealtime();
        while (__hip_atomic_load(&flags[2 * NBLK], __ATOMIC_RELAXED, __HIP_MEMORY_SCOPE_AGENT) < NBLK) {
            __builtin_amdgcn_s_sleep(16);
            if ((long long)__builtin_amdgcn_s_memrealtime() - t0 > TMO_ARRIVE) { s_nowait = 1; break; }
        }
    }

    // add_w for my 8 px: loaded ONCE for all 36 steps
    float4 aw4[2];
    #pragma unroll
    for (int k = 0; k < 2; ++k)
        aw4[k] = *(const float4*)&add_w[(size_t)p * HW + (y0 + oy + k) * W + ox];

    // ---- init: zero sx/sh (h0 = 0; halos/pads/row24 stay 0 unless overwritten) ----
    for (int s = tid; s < SR * SC; s += 512) {
        (&sx[0][0])[s] = 0.f;
        (&sh[0][0])[s] = 0.f;
    }
    __syncthreads();
    // stage x_0 (storage rows 0..23; in-image rows only)
    {
        const float* xt = inputs + (size_t)p * HW;
        #pragma unroll
        for (int k = 0; k < 3; ++k) {
            const int s = tid + 512 * k;          // < 1536 = 24*64
            const int r = s >> 6, c4 = s & 63;
            const int gy = y0 + r - 4;
            if ((unsigned)gy < (unsigned)H) {
                float4 v = *(const float4*)&xt[gy * W + 4 * c4];
                v.x *= gamma; v.y *= gamma; v.z *= gamma; v.w *= gamma;
                lds_store4(&sx[r][6 + 4 * c4], v);
            }
        }
    }
    __syncthreads();

    // phase-1 slot body: band b (srh rows 3b..3b+2), col-group g (cols 4g-4..4g-1)
    auto ph1_slot = [&](int b, int g) {
        const int r0 = 3 * b;           // window storage rows r0..r0+6
        const int c0 = 4 * g;           // window storage cols c0..c0+7 (16B aligned)
        float racc[3][4], hold[3][4];
        #pragma unroll
        for (int k = 0; k < 3; ++k)
            #pragma unroll
            for (int c = 0; c < 4; ++c) racc[k][c] = br;
        #pragma unroll
        for (int ir = 0; ir < 7; ++ir) {
            const float4 xa = *(const float4*)&sx[r0 + ir][c0];
            const float4 xb = *(const float4*)&sx[r0 + ir][c0 + 4];
            const float4 ha = *(const float4*)&sh[r0 + ir][c0];
            const float4 hb = *(const float4*)&sh[r0 + ir][c0 + 4];
            const float vx[8] = {xa.x, xa.y, xa.z, xa.w, xb.x, xb.y, xb.z, xb.w};
            const float vh[8] = {ha.x, ha.y, ha.z, ha.w, hb.x, hb.y, hb.z, hb.w};
            if (ir >= 2 && ir <= 4) {
                #pragma unroll
                for (int c = 0; c < 4; ++c) hold[ir - 2][c] = vh[c + 2];
            }
            #pragma unroll
            for (int k = 0; k < 3; ++k) {
                const int dy = ir - k;
                if (dy >= 0 && dy <= 4) {
                    #pragma unroll
                    for (int dx = 0; dx < 5; ++dx) {
                        const float wx = w_reset[dy * 5 + dx];
                        const float wh = w_reset[25 + dy * 5 + dx];
                        #pragma unroll
                        for (int c = 0; c < 4; ++c) {
                            racc[k][c] = fmaf(vx[c + dx], wx, racc[k][c]);
                            racc[k][c] = fmaf(vh[c + dx], wh, racc[k][c]);
                        }
                    }
                }
            }
        }
        #pragma unroll
        for (int k = 0; k < 3; ++k) {
            if (r0 + k < RR) {
                float4 v;
                v.x = fast_sigmoid(racc[k][0]) * hold[k][0];
                v.y = fast_sigmoid(racc[k][1]) * hold[k][1];
                v.z = fast_sigmoid(racc[k][2]) * hold[k][2];
                v.w = fast_sigmoid(racc[k][3]) * hold[k][3];
                lds_store4(&srh[r0 + k][c0 + 2], v);
            }
        }
    };

    #pragma unroll 1
    for (int t = 0; t < T; ++t) {
        // ---- phase 1: wave-specialized. Waves 0-6 = bands 0-6 (g=lane);
        //      wave 7 = halo duty (poll + global->LDS) + 14 leftover slots. ----
        if (rbb < 7) {
            // edge bands need the halo rows wave 7 is writing
            if (t > 0 && (rbb == 0 || rbb == 1 || rbb == 5 || rbb == 6)) {
                while (__hip_atomic_load(&s_haloready, __ATOMIC_ACQUIRE, __HIP_MEMORY_SCOPE_WORKGROUP) < t)
                    __builtin_amdgcn_s_sleep(1);
            }
            ph1_slot(rbb, lane);
        } else {
            if (t > 0) {
                if (lane == 0 && !s_nowait) {
                    const long long t0 = (long long)__builtin_amdgcn_s_memrealtime();
                    if (band > 0) {
                        while (__hip_atomic_load(&flagsBot[bid - 1], __ATOMIC_RELAXED, __HIP_MEMORY_SCOPE_AGENT) < 2 * t) {
                            __builtin_amdgcn_s_sleep(1);
                            if ((long long)__builtin_amdgcn_s_memrealtime() - t0 > TMO_STEP) { s_nowait = 1; break; }
                        }
                    }
                    if (band < 7) {
                        while (__hip_atomic_load(&flagsTop[bid + 1], __ATOMIC_RELAXED, __HIP_MEMORY_SCOPE_AGENT) < 2 * t) {
                            __builtin_amdgcn_s_sleep(1);
                            if ((long long)__builtin_amdgcn_s_memrealtime() - t0 > TMO_STEP) { s_nowait = 1; break; }
                        }
                    }
                }
                // whole wave reconverges here, then loads 8 halo rows (64 f4/row)
                {
                    float* hb0 = hhalo + (size_t)((t - 1) & 1) * (NBLK * 2048);
                    #pragma unroll
                    for (int r = 0; r < 8; ++r) {
                        if (r < 4) {
                            if (band > 0) {
                                float* src = &hb0[(size_t)(bid - 1) * 2048 + (4 + r) * 256 + 4 * lane];
                                float4 v;
                                v.x = __hip_atomic_load(&src[0], __ATOMIC_RELAXED, __HIP_MEMORY_SCOPE_AGENT);
                                v.y = __hip_atomic_load(&src[1], __ATOMIC_RELAXED, __HIP_MEMORY_SCOPE_AGENT);
                                v.z = __hip_atomic_load(&src[2], __ATOMIC_RELAXED, __HIP_MEMORY_SCOPE_AGENT);
                                v.w = __hip_atomic_load(&src[3], __ATOMIC_RELAXED, __HIP_MEMORY_SCOPE_AGENT);
                                lds_store4(&sh[r][6 + 4 * lane], v);
                            }
                        } else {
                            if (band < 7) {
                                float* src = &hb0[(size_t)(bid + 1) * 2048 + (r - 4) * 256 + 4 * lane];
                                float4 v;
                                v.x = __hip_atomic_load(&src[0], __ATOMIC_RELAXED, __HIP_MEMORY_SCOPE_AGENT);
                                v.y = __hip_atomic_load(&src[1], __ATOMIC_RELAXED, __HIP_MEMORY_SCOPE_AGENT);
                                v.z = __hip_atomic_load(&src[2], __ATOMIC_RELAXED, __HIP_MEMORY_SCOPE_AGENT);
                                v.w = __hip_atomic_load(&src[3], __ATOMIC_RELAXED, __HIP_MEMORY_SCOPE_AGENT);
                                lds_store4(&sh[16 + r][6 + 4 * lane], v);
                            }
                        }
                    }
                }
                asm volatile("s_waitcnt lgkmcnt(0)" ::: "memory");
                if (lane == 0)
                    __hip_atomic_store(&s_haloready, t, __ATOMIC_RELEASE, __HIP_MEMORY_SCOPE_WORKGROUP);
            }
            // leftover slots: lane l<14 -> band l/2, col-group 64+(l&1), one masked pass
            if (lane < 14) ph1_slot(lane >> 1, 64 + (lane & 1));
        }
        __syncthreads();

        // ---- phase 2: interior u, c, h_new (2x4 per thread, all 512 threads) ----
        float4 hn4[2];
        {
            float uacc[2][4], cacc[2][4], hold[2][4];
            #pragma unroll
            for (int k = 0; k < 2; ++k)
                #pragma unroll
                for (int c = 0; c < 4; ++c) { uacc[k][c] = bu; cacc[k][c] = 0.f; }
            #pragma unroll
            for (int ir = 0; ir < 6; ++ir) {
                const int sr = oy + 2 + ir;                 // sx/sh storage row
                const float4 xa = *(const float4*)&sx[sr][ox + 4];
                const float4 xb = *(const float4*)&sx[sr][ox + 8];
                const float4 ha = *(const float4*)&sh[sr][ox + 4];
                const float4 hb = *(const float4*)&sh[sr][ox + 8];
                const float4 ra = *(const float4*)&srh[oy + ir][ox + 4];
                const float4 rb = *(const float4*)&srh[oy + ir][ox + 8];
                const float vx[8] = {xa.x, xa.y, xa.z, xa.w, xb.x, xb.y, xb.z, xb.w};
                const float vh[8] = {ha.x, ha.y, ha.z, ha.w, hb.x, hb.y, hb.z, hb.w};
                const float vr[8] = {ra.x, ra.y, ra.z, ra.w, rb.x, rb.y, rb.z, rb.w};
                if (ir == 2) {
                    #pragma unroll
                    for (int c = 0; c < 4; ++c) hold[0][c] = vh[c + 2];
                }
                if (ir == 3) {
                    #pragma unroll
                    for (int c = 0; c < 4; ++c) hold[1][c] = vh[c + 2];
                }
                #pragma unroll
                for (int k = 0; k < 2; ++k) {
                    const int dy = ir - k;
                    if (dy >= 0 && dy <= 4) {
                        #pragma unroll
                        for (int dx = 0; dx < 5; ++dx) {
                            const float wux = w_update[dy * 5 + dx];
                            const float wuh = w_update[25 + dy * 5 + dx];
                            const float wox = w_out[dy * 5 + dx];
                            const float wor = w_out[25 + dy * 5 + dx];
                            #pragma unroll
                            for (int c = 0; c < 4; ++c) {
                                uacc[k][c] = fmaf(vx[c + dx], wux, uacc[k][c]);
                                uacc[k][c] = fmaf(vh[c + dx], wuh, uacc[k][c]);
                                cacc[k][c] = fmaf(vx[c + dx], wox, cacc[k][c]);
                                cacc[k][c] = fmaf(vr[c + dx], wor, cacc[k][c]);
                            }
                        }
                    }
                }
            }
            #pragma unroll
            for (int k = 0; k < 2; ++k) {
                float hn[4];
                #pragma unroll
                for (int c = 0; c < 4; ++c) {
                    const float u = fast_sigmoid(uacc[k][c]);
                    hn[c] = hold[k][c] + (cacc[k][c] - hold[k][c]) * u;
                }
                hn4[k] = make_float4(hn[0], hn[1], hn[2], hn[3]);
            }
        }
        __syncthreads();   // all reads of sx/sh/srh done

        // ---- phase 3a: halo border stores FIRST + per-wave drain + flag post ----
        if (t + 1 < T) {
            if (rbb < 2 && band > 0) {            // rows 0..3 -> slots 0..3 (read by band-1)
                float* hb = hhalo + (size_t)(t & 1) * (NBLK * 2048) + (size_t)bid * 2048;
                #pragma unroll
                for (int k = 0; k < 2; ++k) {
                    float* d = &hb[(oy + k) * 256 + ox];
                    __hip_atomic_store(&d[0], hn4[k].x, __ATOMIC_RELAXED, __HIP_MEMORY_SCOPE_AGENT);
                    __hip_atomic_store(&d[1], hn4[k].y, __ATOMIC_RELAXED, __HIP_MEMORY_SCOPE_AGENT);
                    __hip_atomic_store(&d[2], hn4[k].z, __ATOMIC_RELAXED, __HIP_MEMORY_SCOPE_AGENT);
                    __hip_atomic_store(&d[3], hn4[k].w, __ATOMIC_RELAXED, __HIP_MEMORY_SCOPE_AGENT);
                }
                asm volatile("s_waitcnt vmcnt(0)" ::: "memory");
                if (lane == 0)
                    __hip_atomic_fetch_add(&flagsTop[bid], 1, __ATOMIC_RELAXED, __HIP_MEMORY_SCOPE_AGENT);
            }
            if (rbb >= 6 && band < 7) {           // rows 12..15 -> slots 4..7 (read by band+1)
                float* hb = hhalo + (size_t)(t & 1) * (NBLK * 2048) + (size_t)bid * 2048;
                #pragma unroll
                for (int k = 0; k < 2; ++k) {
                    float* d = &hb[(oy + k - 8) * 256 + ox];
                    __hip_atomic_store(&d[0], hn4[k].x, __ATOMIC_RELAXED, __HIP_MEMORY_SCOPE_AGENT);
                    __hip_atomic_store(&d[1], hn4[k].y, __ATOMIC_RELAXED, __HIP_MEMORY_SCOPE_AGENT);
                    __hip_atomic_store(&d[2], hn4[k].z, __ATOMIC_RELAXED, __HIP_MEMORY_SCOPE_AGENT);
                    __hip_atomic_store(&d[3], hn4[k].w, __ATOMIC_RELAXED, __HIP_MEMORY_SCOPE_AGENT);
                }
                asm volatile("s_waitcnt vmcnt(0)" ::: "memory");
                if (lane == 0)
                    __hip_atomic_fetch_add(&flagsBot[bid], 1, __ATOMIC_RELAXED, __HIP_MEMORY_SCOPE_AGENT);
            }
        }

        // ---- phase 3b: issue x_{t+1} loads -> regs, sh commit, xs epilogue
        //      (covers load latency), staging LDS writes ----
        float4 xp[3];
        if (t + 1 < T) {
            const float* xt = inputs + (size_t)(t + 1) * PHW + (size_t)p * HW;
            #pragma unroll
            for (int k = 0; k < 3; ++k) {
                const int s = tid + 512 * k;      // rows 0..23
                const int r = s >> 6, c4 = s & 63;
                const int gy = y0 + r - 4;
                xp[k] = make_float4(0.f, 0.f, 0.f, 0.f);
                if ((unsigned)gy < (unsigned)H)
                    xp[k] = *(const float4*)&xt[gy * W + 4 * c4];
            }
            #pragma unroll
            for (int k = 0; k < 2; ++k)
                lds_store4(&sh[4 + oy + k][6 + ox], hn4[k]);
        }
        {
            float* xso = xs + (size_t)t * PHW + (size_t)p * HW;
            #pragma unroll
            for (int k = 0; k < 2; ++k) {
                vfloat4 v;
                v.x = fast_tanh(hn4[k].x) * aw4[k].x;
                v.y = fast_tanh(hn4[k].y) * aw4[k].y;
                v.z = fast_tanh(hn4[k].z) * aw4[k].z;
                v.w = fast_tanh(hn4[k].w) * aw4[k].w;
                __builtin_nontemporal_store(v, (vfloat4*)&xso[(y0 + oy + k) * W + ox]);
            }
        }
        if (t + 1 >= T) break;
        {
            #pragma unroll
            for (int k = 0; k < 3; ++k) {
                const int s = tid + 512 * k;
                const int r = s >> 6, c4 = s & 63;
                const int gy = y0 + r - 4;
                if ((unsigned)gy < (unsigned)H) {
                    float4 v = xp[k];
                    v.x *= gamma; v.y *= gamma; v.z *= gamma; v.w *= gamma;
                    lds_store4(&sx[r][6 + 4 * c4], v);
                }
            }
        }
        __syncthreads();   // staging + sh commit visible; next ph1 may start
    }
}

// out_y[t,y,x] = bias[y,x] + sum_p xs[t,p,y,x], float4 per thread
__global__ __launch_bounds__(256) void reduce_out(
    const float* __restrict__ xs, const float* __restrict__ bias,
    float* __restrict__ out_y)
{
    const int i4  = blockIdx.x * 256 + threadIdx.x;      // < T*HW/4 = 294912
    const int t   = i4 / (HW / 4);
    const int yx4 = i4 - t * (HW / 4);
    const float4* __restrict__ src = (const float4*)(xs + (size_t)t * PHW) + yx4;
    const float4  b4 = ((const float4*)bias)[yx4];
    float a0[4] = {b4.x, b4.y, b4.z, b4.w};
    float a1[4] = {0.f, 0.f, 0.f, 0.f};
    #pragma unroll 8
    for (int p = 0; p < P; p += 2) {
        const float4 v0 = src[(size_t)p * (HW / 4)];
        const float4 v1 = src[(size_t)(p + 1) * (HW / 4)];
        a0[0] += v0.x; a0[1] += v0.y; a0[2] += v0.z; a0[3] += v0.w;
        a1[0] += v1.x; a1[1] += v1.y; a1[2] += v1.z; a1[3] += v1.w;
    }
    ((float4*)out_y)[i4] = make_float4(a0[0] + a1[0], a0[1] + a1[1],
                                       a0[2] + a1[2], a0[3] + a1[3]);
}

extern "C" void kernel_launch(void* const* d_in, const int* in_sizes, int n_in,
                              void* d_out, int out_size, void* d_ws, size_t ws_size,
                              hipStream_t stream) {
    const float* inputs   = (const float*)d_in[0];
    const float* w_reset  = (const float*)d_in[1];
    const float* b_reset  = (const float*)d_in[2];
    const float* w_update = (const float*)d_in[3];
    const float* b_update = (const float*)d_in[4];
    const float* w_out    = (const float*)d_in[5];
    const float* gam      = (const float*)d_in[6];
    const float* add_w    = (const float*)d_in[7];
    const float* bias     = (const float*)d_in[8];

    float* out_y = (float*)d_out;                 // T*H*W
    float* xs    = out_y + (size_t)T * HW;        // T*P*H*W

    float* hhalo = (float*)d_ws;                  // 2 parities x 512 blocks x 8x256 floats
    int*   flags = (int*)((char*)d_ws + (size_t)2 * NBLK * 2048 * sizeof(float));

    // flags[0..NBLK) top counters, [NBLK..2*NBLK) bottom, [2*NBLK] arrival
    (void)hipMemsetAsync(flags, 0, (2 * NBLK + 1) * sizeof(int), stream);

    gru_all<<<dim3(NBLK), dim3(512), 0, stream>>>(
        inputs, gam, w_update, b_update, w_reset, b_reset, w_out, add_w,
        xs, hhalo, flags);

    const int nout4 = T * HW / 4;                 // 294912
    reduce_out<<<nout4 / 256, 256, 0, stream>>>(xs, bias, out_y);
}

// Round 15
// 761.808 us; speedup vs baseline: 1.2701x; 1.2701x over previous
//
#include <hip/hip_runtime.h>

constexpr int T = 36, P = 64, H = 128, W = 256;
constexpr int HW  = H * W;        // 32768
constexpr int PHW = P * HW;       // 2097152

constexpr int TH   = 16;          // rows per band
constexpr int NB   = 8;           // bands per plane
constexpr int NBLK = P * NB;      // 512 blocks (2 per CU), 512 threads each
// sx/sh: storage row = spatial + 4 (spatial -4..19 -> 0..23; row 24 = zero pad)
//        storage col = spatial + 6 (in-image 0..255 -> 6..261; pads stay 0)
constexpr int SR = 25, SC = 268;
// srh: storage row = spatial + 2 (spatial -2..17 -> 0..19), same col mapping
constexpr int RR = 20;

constexpr long long TMO_ARRIVE = 3000000;   // ~30 ms @100MHz wall clock
constexpr long long TMO_STEP   = 1000000;   // ~10 ms

typedef float vfloat4 __attribute__((ext_vector_type(4)));

__device__ __forceinline__ float fast_sigmoid(float z) {
    float e = __expf(-z);
    return __builtin_amdgcn_rcpf(1.0f + e);
}
__device__ __forceinline__ float fast_tanh(float x) {
    float e = __expf(-2.0f * fabsf(x));
    float t = (1.0f - e) * __builtin_amdgcn_rcpf(1.0f + e);
    return copysignf(t, x);
}

__device__ __forceinline__ void lds_store4(float* d, float4 v) {
    // 8B-aligned LDS store of 16B (storage col base ≡ 2 mod 4)
    *(float2*)d       = make_float2(v.x, v.y);
    *(float2*)(d + 2) = make_float2(v.z, v.w);
}

__global__ __launch_bounds__(512, 4) void gru_all(
    const float* __restrict__ inputs, const float* __restrict__ gam,
    const float* __restrict__ w_update, const float* __restrict__ b_update,
    const float* __restrict__ w_reset,  const float* __restrict__ b_reset,
    const float* __restrict__ w_out,    const float* __restrict__ add_w,
    float* __restrict__ xs, float* __restrict__ hhalo, int* __restrict__ flags)
{
    __shared__ __align__(16) float sx[SR][SC];
    __shared__ __align__(16) float sh[SR][SC];
    __shared__ __align__(16) float srh[RR][SC];
    __shared__ int s_nowait;

    const int tid  = threadIdx.x;
    const int bid  = blockIdx.x;
    const int p    = bid >> 3;
    const int band = bid & 7;
    const int y0   = band * TH;

    const float gamma = gam[p];
    const float bu = b_update[0];
    const float br = b_reset[0];

    // interior mapping: 2x4 px per thread (8 waves, each owns 2 output rows)
    const int cg = tid & 63, rbb = tid >> 6;    // cg 0..63, rbb 0..7
    const int ox = 4 * cg,   oy  = 2 * rbb;

    int* flagsTop = flags;
    int* flagsBot = flags + NBLK;

    // ---- arrival barrier (relaxed counting) with timeout ----
    if (tid == 0) {
        s_nowait = 0;
        __hip_atomic_fetch_add(&flags[2 * NBLK], 1, __ATOMIC_RELAXED, __HIP_MEMORY_SCOPE_AGENT);
        const long long t0 = (long long)__builtin_amdgcn_s_memrealtime();
        while (__hip_atomic_load(&flags[2 * NBLK], __ATOMIC_RELAXED, __HIP_MEMORY_SCOPE_AGENT) < NBLK) {
            __builtin_amdgcn_s_sleep(16);
            if ((long long)__builtin_amdgcn_s_memrealtime() - t0 > TMO_ARRIVE) { s_nowait = 1; break; }
        }
    }

    // add_w for my 8 px: loaded ONCE for all 36 steps
    float4 aw4[2];
    #pragma unroll
    for (int k = 0; k < 2; ++k)
        aw4[k] = *(const float4*)&add_w[(size_t)p * HW + (y0 + oy + k) * W + ox];

    // ---- init: zero sx/sh (h0 = 0; halos/pads/row24 stay 0 unless overwritten) ----
    for (int s = tid; s < SR * SC; s += 512) {
        (&sx[0][0])[s] = 0.f;
        (&sh[0][0])[s] = 0.f;
    }
    __syncthreads();
    // stage x_0 (storage rows 0..23; in-image rows only)
    {
        const float* xt = inputs + (size_t)p * HW;
        #pragma unroll
        for (int k = 0; k < 3; ++k) {
            const int s = tid + 512 * k;          // < 1536 = 24*64
            const int r = s >> 6, c4 = s & 63;
            const int gy = y0 + r - 4;
            if ((unsigned)gy < (unsigned)H) {
                float4 v = *(const float4*)&xt[gy * W + 4 * c4];
                v.x *= gamma; v.y *= gamma; v.z *= gamma; v.w *= gamma;
                lds_store4(&sx[r][6 + 4 * c4], v);
            }
        }
    }
    __syncthreads();

    float4 hn4_prev[2];   // h_new of step t-1, flushed to xs at top of step t

    #pragma unroll 1
    for (int t = 0; t < T; ++t) {
        // ---- pipelined xs epilogue for step t-1: stores retire under phase 1 ----
        if (t > 0) {
            float* xso = xs + (size_t)(t - 1) * PHW + (size_t)p * HW;
            #pragma unroll
            for (int k = 0; k < 2; ++k) {
                vfloat4 v;
                v.x = fast_tanh(hn4_prev[k].x) * aw4[k].x;
                v.y = fast_tanh(hn4_prev[k].y) * aw4[k].y;
                v.z = fast_tanh(hn4_prev[k].z) * aw4[k].z;
                v.w = fast_tanh(hn4_prev[k].w) * aw4[k].w;
                __builtin_nontemporal_store(v, (vfloat4*)&xso[(y0 + oy + k) * W + ox]);
            }
        }

        // ---- phase 1: reset + r*h, 3x4 blocking, 7 bands x 66 col-groups = 462 slots ----
        if (tid < 462) {
            const int b  = tid / 66;        // 0..6 -> srh storage rows 3b..3b+2
            const int g  = tid - 66 * b;    // 0..65 -> spatial cols 4g-4..4g-1
            const int r0 = 3 * b;           // window storage rows r0..r0+6
            const int c0 = 4 * g;           // window storage cols c0..c0+7 (16B aligned)
            float racc[3][4], hold[3][4];
            #pragma unroll
            for (int k = 0; k < 3; ++k)
                #pragma unroll
                for (int c = 0; c < 4; ++c) racc[k][c] = br;
            #pragma unroll
            for (int ir = 0; ir < 7; ++ir) {
                const float4 xa = *(const float4*)&sx[r0 + ir][c0];
                const float4 xb = *(const float4*)&sx[r0 + ir][c0 + 4];
                const float4 ha = *(const float4*)&sh[r0 + ir][c0];
                const float4 hb = *(const float4*)&sh[r0 + ir][c0 + 4];
                const float vx[8] = {xa.x, xa.y, xa.z, xa.w, xb.x, xb.y, xb.z, xb.w};
                const float vh[8] = {ha.x, ha.y, ha.z, ha.w, hb.x, hb.y, hb.z, hb.w};
                if (ir >= 2 && ir <= 4) {
                    #pragma unroll
                    for (int c = 0; c < 4; ++c) hold[ir - 2][c] = vh[c + 2];
                }
                #pragma unroll
                for (int k = 0; k < 3; ++k) {
                    const int dy = ir - k;
                    if (dy >= 0 && dy <= 4) {
                        #pragma unroll
                        for (int dx = 0; dx < 5; ++dx) {
                            const float wx = w_reset[dy * 5 + dx];
                            const float wh = w_reset[25 + dy * 5 + dx];
                            #pragma unroll
                            for (int c = 0; c < 4; ++c) {
                                racc[k][c] = fmaf(vx[c + dx], wx, racc[k][c]);
                                racc[k][c] = fmaf(vh[c + dx], wh, racc[k][c]);
                            }
                        }
                    }
                }
            }
            #pragma unroll
            for (int k = 0; k < 3; ++k) {
                if (r0 + k < RR) {
                    float4 v;
                    v.x = fast_sigmoid(racc[k][0]) * hold[k][0];
                    v.y = fast_sigmoid(racc[k][1]) * hold[k][1];
                    v.z = fast_sigmoid(racc[k][2]) * hold[k][2];
                    v.w = fast_sigmoid(racc[k][3]) * hold[k][3];
                    lds_store4(&srh[r0 + k][c0 + 2], v);
                }
            }
        }
        __syncthreads();

        // ---- phase 2: interior u, c, h_new (2x4 per thread, all 512 threads) ----
        float4 hn4[2];
        {
            float uacc[2][4], cacc[2][4], hold[2][4];
            #pragma unroll
            for (int k = 0; k < 2; ++k)
                #pragma unroll
                for (int c = 0; c < 4; ++c) { uacc[k][c] = bu; cacc[k][c] = 0.f; }
            #pragma unroll
            for (int ir = 0; ir < 6; ++ir) {
                const int sr = oy + 2 + ir;                 // sx/sh storage row
                const float4 xa = *(const float4*)&sx[sr][ox + 4];
                const float4 xb = *(const float4*)&sx[sr][ox + 8];
                const float4 ha = *(const float4*)&sh[sr][ox + 4];
                const float4 hb = *(const float4*)&sh[sr][ox + 8];
                const float4 ra = *(const float4*)&srh[oy + ir][ox + 4];
                const float4 rb = *(const float4*)&srh[oy + ir][ox + 8];
                const float vx[8] = {xa.x, xa.y, xa.z, xa.w, xb.x, xb.y, xb.z, xb.w};
                const float vh[8] = {ha.x, ha.y, ha.z, ha.w, hb.x, hb.y, hb.z, hb.w};
                const float vr[8] = {ra.x, ra.y, ra.z, ra.w, rb.x, rb.y, rb.z, rb.w};
                if (ir == 2) {
                    #pragma unroll
                    for (int c = 0; c < 4; ++c) hold[0][c] = vh[c + 2];
                }
                if (ir == 3) {
                    #pragma unroll
                    for (int c = 0; c < 4; ++c) hold[1][c] = vh[c + 2];
                }
                #pragma unroll
                for (int k = 0; k < 2; ++k) {
                    const int dy = ir - k;
                    if (dy >= 0 && dy <= 4) {
                        #pragma unroll
                        for (int dx = 0; dx < 5; ++dx) {
                            const float wux = w_update[dy * 5 + dx];
                            const float wuh = w_update[25 + dy * 5 + dx];
                            const float wox = w_out[dy * 5 + dx];
                            const float wor = w_out[25 + dy * 5 + dx];
                            #pragma unroll
                            for (int c = 0; c < 4; ++c) {
                                uacc[k][c] = fmaf(vx[c + dx], wux, uacc[k][c]);
                                uacc[k][c] = fmaf(vh[c + dx], wuh, uacc[k][c]);
                                cacc[k][c] = fmaf(vx[c + dx], wox, cacc[k][c]);
                                cacc[k][c] = fmaf(vr[c + dx], wor, cacc[k][c]);
                            }
                        }
                    }
                }
            }
            #pragma unroll
            for (int k = 0; k < 2; ++k) {
                float hn[4];
                #pragma unroll
                for (int c = 0; c < 4; ++c) {
                    const float u = fast_sigmoid(uacc[k][c]);
                    hn[c] = hold[k][c] + (cacc[k][c] - hold[k][c]) * u;
                }
                hn4[k] = make_float4(hn[0], hn[1], hn[2], hn[3]);
            }
        }
        __syncthreads();   // all reads of sx/sh/srh done

        // ---- phase 3a: halo stores FIRST + per-wave drain + early flag post ----
        if (t + 1 < T) {
            if (rbb < 2 && band > 0) {            // rows 0..3 -> slots 0..3 (read by band-1)
                float* hb = hhalo + (size_t)(t & 1) * (NBLK * 2048) + (size_t)bid * 2048;
                #pragma unroll
                for (int k = 0; k < 2; ++k) {
                    float* d = &hb[(oy + k) * 256 + ox];
                    __hip_atomic_store(&d[0], hn4[k].x, __ATOMIC_RELAXED, __HIP_MEMORY_SCOPE_AGENT);
                    __hip_atomic_store(&d[1], hn4[k].y, __ATOMIC_RELAXED, __HIP_MEMORY_SCOPE_AGENT);
                    __hip_atomic_store(&d[2], hn4[k].z, __ATOMIC_RELAXED, __HIP_MEMORY_SCOPE_AGENT);
                    __hip_atomic_store(&d[3], hn4[k].w, __ATOMIC_RELAXED, __HIP_MEMORY_SCOPE_AGENT);
                }
                asm volatile("s_waitcnt vmcnt(0)" ::: "memory");
                if (cg == 0)
                    __hip_atomic_fetch_add(&flagsTop[bid], 1, __ATOMIC_RELAXED, __HIP_MEMORY_SCOPE_AGENT);
            }
            if (rbb >= 6 && band < 7) {           // rows 12..15 -> slots 4..7 (read by band+1)
                float* hb = hhalo + (size_t)(t & 1) * (NBLK * 2048) + (size_t)bid * 2048;
                #pragma unroll
                for (int k = 0; k < 2; ++k) {
                    float* d = &hb[(oy + k - 8) * 256 + ox];
                    __hip_atomic_store(&d[0], hn4[k].x, __ATOMIC_RELAXED, __HIP_MEMORY_SCOPE_AGENT);
                    __hip_atomic_store(&d[1], hn4[k].y, __ATOMIC_RELAXED, __HIP_MEMORY_SCOPE_AGENT);
                    __hip_atomic_store(&d[2], hn4[k].z, __ATOMIC_RELAXED, __HIP_MEMORY_SCOPE_AGENT);
                    __hip_atomic_store(&d[3], hn4[k].w, __ATOMIC_RELAXED, __HIP_MEMORY_SCOPE_AGENT);
                }
                asm volatile("s_waitcnt vmcnt(0)" ::: "memory");
                if (cg == 0)
                    __hip_atomic_fetch_add(&flagsBot[bid], 1, __ATOMIC_RELAXED, __HIP_MEMORY_SCOPE_AGENT);
            }
        }

        // ---- phase 3b: LDS commits + x_{t+1} staging (direct load->LDS) ----
        #pragma unroll
        for (int k = 0; k < 2; ++k)
            lds_store4(&sh[4 + oy + k][6 + ox], hn4[k]);
        if (t + 1 < T) {
            const float* xt = inputs + (size_t)(t + 1) * PHW + (size_t)p * HW;
            #pragma unroll
            for (int k = 0; k < 3; ++k) {
                const int s = tid + 512 * k;      // rows 0..23
                const int r = s >> 6, c4 = s & 63;
                const int gy = y0 + r - 4;
                if ((unsigned)gy < (unsigned)H) {
                    float4 v = *(const float4*)&xt[gy * W + 4 * c4];
                    v.x *= gamma; v.y *= gamma; v.z *= gamma; v.w *= gamma;
                    lds_store4(&sx[r][6 + 4 * c4], v);
                }
            }
        }

        hn4_prev[0] = hn4[0];
        hn4_prev[1] = hn4[1];
        if (t + 1 >= T) break;

        // ---- phase 4: neighbor wait (waiter lanes poll; others idle at barrier) ----
        if (tid == 0 && band > 0 && !s_nowait) {
            const long long t0 = (long long)__builtin_amdgcn_s_memrealtime();
            while (__hip_atomic_load(&flagsBot[bid - 1], __ATOMIC_RELAXED, __HIP_MEMORY_SCOPE_AGENT) < 2 * (t + 1)) {
                __builtin_amdgcn_s_sleep(1);
                if ((long long)__builtin_amdgcn_s_memrealtime() - t0 > TMO_STEP) { s_nowait = 1; break; }
            }
        }
        if (tid == 64 && band < 7 && !s_nowait) {
            const long long t0 = (long long)__builtin_amdgcn_s_memrealtime();
            while (__hip_atomic_load(&flagsTop[bid + 1], __ATOMIC_RELAXED, __HIP_MEMORY_SCOPE_AGENT) < 2 * (t + 1)) {
                __builtin_amdgcn_s_sleep(1);
                if ((long long)__builtin_amdgcn_s_memrealtime() - t0 > TMO_STEP) { s_nowait = 1; break; }
            }
        }
        __syncthreads();

        // ---- phase 5: read neighbor h borders into LDS halo rows ----
        {
            float* hb0 = hhalo + (size_t)(t & 1) * (NBLK * 2048);
            const int r = tid >> 6, c4 = tid & 63;   // 512 slots, one pass
            if (r < 4) {
                if (band > 0) {
                    float* src = &hb0[(size_t)(bid - 1) * 2048 + (4 + r) * 256 + 4 * c4];
                    float4 v;
                    v.x = __hip_atomic_load(&src[0], __ATOMIC_RELAXED, __HIP_MEMORY_SCOPE_AGENT);
                    v.y = __hip_atomic_load(&src[1], __ATOMIC_RELAXED, __HIP_MEMORY_SCOPE_AGENT);
                    v.z = __hip_atomic_load(&src[2], __ATOMIC_RELAXED, __HIP_MEMORY_SCOPE_AGENT);
                    v.w = __hip_atomic_load(&src[3], __ATOMIC_RELAXED, __HIP_MEMORY_SCOPE_AGENT);
                    lds_store4(&sh[r][6 + 4 * c4], v);
                }
            } else {
                if (band < 7) {
                    float* src = &hb0[(size_t)(bid + 1) * 2048 + (r - 4) * 256 + 4 * c4];
                    float4 v;
                    v.x = __hip_atomic_load(&src[0], __ATOMIC_RELAXED, __HIP_MEMORY_SCOPE_AGENT);
                    v.y = __hip_atomic_load(&src[1], __ATOMIC_RELAXED, __HIP_MEMORY_SCOPE_AGENT);
                    v.z = __hip_atomic_load(&src[2], __ATOMIC_RELAXED, __HIP_MEMORY_SCOPE_AGENT);
                    v.w = __hip_atomic_load(&src[3], __ATOMIC_RELAXED, __HIP_MEMORY_SCOPE_AGENT);
                    lds_store4(&sh[16 + r][6 + 4 * c4], v);
                }
            }
        }
        __syncthreads();
    }

    // ---- final xs epilogue (step T-1) ----
    {
        float* xso = xs + (size_t)(T - 1) * PHW + (size_t)p * HW;
        #pragma unroll
        for (int k = 0; k < 2; ++k) {
            vfloat4 v;
            v.x = fast_tanh(hn4_prev[k].x) * aw4[k].x;
            v.y = fast_tanh(hn4_prev[k].y) * aw4[k].y;
            v.z = fast_tanh(hn4_prev[k].z) * aw4[k].z;
            v.w = fast_tanh(hn4_prev[k].w) * aw4[k].w;
            __builtin_nontemporal_store(v, (vfloat4*)&xso[(y0 + oy + k) * W + ox]);
        }
    }
}

// out_y[t,y,x] = bias[y,x] + sum_p xs[t,p,y,x], float4 per thread
__global__ __launch_bounds__(256) void reduce_out(
    const float* __restrict__ xs, const float* __restrict__ bias,
    float* __restrict__ out_y)
{
    const int i4  = blockIdx.x * 256 + threadIdx.x;      // < T*HW/4 = 294912
    const int t   = i4 / (HW / 4);
    const int yx4 = i4 - t * (HW / 4);
    const float4* __restrict__ src = (const float4*)(xs + (size_t)t * PHW) + yx4;
    const float4  b4 = ((const float4*)bias)[yx4];
    float a0[4] = {b4.x, b4.y, b4.z, b4.w};
    float a1[4] = {0.f, 0.f, 0.f, 0.f};
    #pragma unroll 8
    for (int p = 0; p < P; p += 2) {
        const float4 v0 = src[(size_t)p * (HW / 4)];
        const float4 v1 = src[(size_t)(p + 1) * (HW / 4)];
        a0[0] += v0.x; a0[1] += v0.y; a0[2] += v0.z; a0[3] += v0.w;
        a1[0] += v1.x; a1[1] += v1.y; a1[2] += v1.z; a1[3] += v1.w;
    }
    ((float4*)out_y)[i4] = make_float4(a0[0] + a1[0], a0[1] + a1[1],
                                       a0[2] + a1[2], a0[3] + a1[3]);
}

extern "C" void kernel_launch(void* const* d_in, const int* in_sizes, int n_in,
                              void* d_out, int out_size, void* d_ws, size_t ws_size,
                              hipStream_t stream) {
    const float* inputs   = (const float*)d_in[0];
    const float* w_reset  = (const float*)d_in[1];
    const float* b_reset  = (const float*)d_in[2];
    const float* w_update = (const float*)d_in[3];
    const float* b_update = (const float*)d_in[4];
    const float* w_out    = (const float*)d_in[5];
    const float* gam      = (const float*)d_in[6];
    const float* add_w    = (const float*)d_in[7];
    const float* bias     = (const float*)d_in[8];

    float* out_y = (float*)d_out;                 // T*H*W
    float* xs    = out_y + (size_t)T * HW;        // T*P*H*W

    float* hhalo = (float*)d_ws;                  // 2 parities x 512 blocks x 8x256 floats
    int*   flags = (int*)((char*)d_ws + (size_t)2 * NBLK * 2048 * sizeof(float));

    // flags[0..NBLK) top counters, [NBLK..2*NBLK) bottom, [2*NBLK] arrival
    (void)hipMemsetAsync(flags, 0, (2 * NBLK + 1) * sizeof(int), stream);

    gru_all<<<dim3(NBLK), dim3(512), 0, stream>>>(
        inputs, gam, w_update, b_update, w_reset, b_reset, w_out, add_w,
        xs, hhalo, flags);

    const int nout4 = T * HW / 4;                 // 294912
    reduce_out<<<nout4 / 256, 256, 0, stream>>>(xs, bias, out_y);
}